// Round 1
// baseline (359.478 us; speedup 1.0000x reference)
//
#include <hip/hip_runtime.h>
#include <hip/hip_bf16.h>

using bf16 = __hip_bfloat16;
typedef __attribute__((ext_vector_type(8))) short bf16x8;   // 8 bf16 in 4 VGPRs
typedef __attribute__((ext_vector_type(4))) short bf16x4;   // 4 bf16 in 2 VGPRs
typedef __attribute__((ext_vector_type(4))) float f32x4;

// async global->LDS, 16B per lane; LDS dest = wave-uniform base + lane*16
typedef const __attribute__((address_space(1))) void* as1_t;
typedef __attribute__((address_space(3))) void* as3_t;
__device__ __forceinline__ void load_lds16(const void* g, void* l) {
    __builtin_amdgcn_global_load_lds((as1_t)g, (as3_t)l, 16, 0, 0);
}

// ---------------- elementwise cast f32 -> bf16 (x) ----------------
__global__ __launch_bounds__(256) void cast_f32_bf16(const float* __restrict__ src,
                                                     bf16* __restrict__ dst, int n4) {
    int i = (blockIdx.x * 256 + threadIdx.x);
    if (i >= n4) return;
    const float4 v = *(const float4*)(src + (long)i * 4);
    bf16 t[4];
    t[0] = __float2bfloat16(v.x);
    t[1] = __float2bfloat16(v.y);
    t[2] = __float2bfloat16(v.z);
    t[3] = __float2bfloat16(v.w);
    *(uint2*)(dst + (long)i * 4) = *(uint2*)t;
}

// ---------------- tiled transpose-cast: src[K][N] f32 -> dst[N][K] bf16 ----------------
__global__ __launch_bounds__(256) void transpose_cast(const float* __restrict__ src,
                                                      int K, int N, bf16* __restrict__ dst) {
    __shared__ float tile[32][33];
    const int tx = threadIdx.x & 31;
    const int ty = threadIdx.x >> 5;   // 0..7
    const int n0 = blockIdx.x * 32;
    const int k0 = blockIdx.y * 32;
    for (int i = 0; i < 32; i += 8)
        tile[ty + i][tx] = src[(long)(k0 + ty + i) * N + n0 + tx];
    __syncthreads();
    for (int i = 0; i < 32; i += 8)
        dst[(long)(n0 + ty + i) * K + k0 + tx] = __float2bfloat16(tile[tx][ty + i]);
}

// ---------------- V transpose via LDS tile: qkv[8192][1536] -> vt[b][kvh][64][2048] ----------------
__global__ __launch_bounds__(256) void transpose_v(const bf16* __restrict__ qkv,
                                                   bf16* __restrict__ vt) {
    __shared__ bf16 tile[64][72];
    const int tb = blockIdx.x, kvh = blockIdx.y, b = blockIdx.z;
    const int r = threadIdx.x >> 3;          // 0..31
    const int c = (threadIdx.x & 7) * 8;     // 0..56
    const bf16* src = qkv + (long)(b * 2048 + tb * 64) * 1536 + 1280 + kvh * 64;
    *(uint4*)&tile[r][c]      = *(const uint4*)(src + (long)r * 1536 + c);
    *(uint4*)&tile[r + 32][c] = *(const uint4*)(src + (long)(r + 32) * 1536 + c);
    __syncthreads();
    bf16* dst = vt + (long)(b * 4 + kvh) * 64 * 2048 + tb * 64;
#pragma unroll
    for (int rr = 0; rr < 2; rr++) {
        const int d = r + rr * 32;
        bf16 t8[8];
#pragma unroll
        for (int e = 0; e < 8; e++) t8[e] = tile[c + e][d];
        *(uint4*)(dst + (long)d * 2048 + c) = *(uint4*)t8;
    }
}

// ---------------- GEMM (m97 structure): C[M][N] = A[M][K] * Bt[N][K]^T ----------------
template <bool BF16_OUT>
__global__ __launch_bounds__(256) void gemm_bt(const bf16* __restrict__ A,
                                               const bf16* __restrict__ Bt,
                                               void* __restrict__ C,
                                               int M, int N, int K) {
    __shared__ bf16 Ash[128 * 32];
    __shared__ bf16 Bsh[128 * 32];
    const int tid  = threadIdx.x;
    const int lane = tid & 63;
    const int wid  = tid >> 6;
    const int wm   = (wid >> 1) * 64;
    const int wn   = (wid & 1) * 64;
    const int quad = lane >> 4;
    const int l16  = lane & 15;
    const int bm = blockIdx.x, bn = blockIdx.y;

    const int r_l   = lane >> 2;                 // 0..15
    const int cslot = lane & 3;
    const int cdat  = (cslot - (r_l >> 1)) & 3;  // swizzled source chunk

    const bf16* pa0 = A  + (long)(bm * 128 + wid * 32 + r_l) * K + cdat * 8;
    const bf16* pa1 = pa0 + (long)16 * K;
    const bf16* pb0 = Bt + (long)(bn * 128 + wid * 32 + r_l) * K + cdat * 8;
    const bf16* pb1 = pb0 + (long)16 * K;
    bf16* la0 = Ash + (wid * 32) * 32;
    bf16* la1 = Ash + (wid * 32 + 16) * 32;
    bf16* lb0 = Bsh + (wid * 32) * 32;
    bf16* lb1 = Bsh + (wid * 32 + 16) * 32;

    const int sw = ((quad + (l16 >> 1)) & 3) * 8;   // swizzled chunk for frag reads

    f32x4 acc[4][4] = {};

    for (int k0 = 0; k0 < K; k0 += 32) {
        __syncthreads();
        load_lds16(pa0 + k0, la0);
        load_lds16(pa1 + k0, la1);
        load_lds16(pb0 + k0, lb0);
        load_lds16(pb1 + k0, lb1);
        __syncthreads();

        bf16x8 af[4], bfr[4];
#pragma unroll
        for (int i = 0; i < 4; i++) af[i]  = *(const bf16x8*)&Ash[(wm + i * 16 + l16) * 32 + sw];
#pragma unroll
        for (int j = 0; j < 4; j++) bfr[j] = *(const bf16x8*)&Bsh[(wn + j * 16 + l16) * 32 + sw];
#pragma unroll
        for (int i = 0; i < 4; i++)
#pragma unroll
            for (int j = 0; j < 4; j++)
                acc[i][j] = __builtin_amdgcn_mfma_f32_16x16x32_bf16(af[i], bfr[j], acc[i][j], 0, 0, 0);
    }

#pragma unroll
    for (int i = 0; i < 4; i++) {
#pragma unroll
        for (int r = 0; r < 4; r++) {
            const long row = (long)(bm * 128 + wm + i * 16 + quad * 4 + r);
#pragma unroll
            for (int j = 0; j < 4; j++) {
                const int col = bn * 128 + wn + j * 16 + l16;
                const float v = acc[i][j][r];
                if (BF16_OUT) ((bf16*)C)[row * N + col] = __float2bfloat16(v);
                else          ((float*)C)[row * N + col] = v;
            }
        }
    }
}

// ---------------- flash attention v8: v7 + KVBLK=128 + XOR-swizzled LDS + setprio ----------------
// grid: (T/128, NH, B) = (16,16,4); 256 threads = 4 waves; wave owns 16 q rows.
// Each block processes TWO q-blocks {31-pb, pb}: nIter = qb/2+1 over 128-kv tiles;
// sum over both segs = 17 iters for every pb -> zero causal imbalance.
// KVBLK=128 halves barrier count vs v7. LDS layout is chunk-XOR swizzled
// (chunk ^= row&7 for K, chunk ^= row&15 for V) -> bank-uniform ds reads+writes
// (v7's [64][72] pad left Vsh b64 reads ~4-way conflicted; padding cannot fix the
//  l16 +/-8 alias while keeping 16B alignment, XOR swizzle can).
// S^T = mfma(K_frag, Q_frag); P stays in registers; l via ones-MFMA (matrix pipe);
// Q pre-scaled so p=exp2(s); next tile reg-prefetched before compute; s_setprio
// wraps MFMA clusters (T5).
__global__ __launch_bounds__(256, 4) void attn_kernel(const bf16* __restrict__ qkv,
                                                      const bf16* __restrict__ vt,
                                                      bf16* __restrict__ attn) {
    __shared__ bf16 Ksh[128 * 64];    // [kv][d], 8-elem chunks XOR-swizzled by row&7
    __shared__ bf16 Vsh[64 * 128];    // [d][kv], 8-elem chunks XOR-swizzled by row&15

    const int tid  = threadIdx.x;
    const int lane = tid & 63;
    const int wid  = tid >> 6;
    const int quad = lane >> 4;
    const int l16  = lane & 15;
    const int h    = blockIdx.y;
    const int b    = blockIdx.z;
    const int kvh  = h >> 2;
    const int pb   = blockIdx.x;      // 0..15

    const float ls = 0.125f * 1.44269504f;   // 1/sqrt(64) * log2(e)

    // ones fragment for l-accumulation MFMA (A[m][k] = 1.0)
    bf16x4 ones;
    { short o1 = (short)0x3F80; short t4[4] = {o1, o1, o1, o1}; ones = *(const bf16x4*)t4; }

    const bf16* kg = qkv + (long)(b * 2048) * 1536 + 1024 + kvh * 64;
    const bf16* vg = vt + (long)(b * 4 + kvh) * 64 * 2048;

    // staging: K tile 128x64 (4 rows/thread), V tile 64x128 (4 rows/thread)
    const int rK = tid >> 3;           // 0..31
    const int cK = (tid & 7) * 8;      // 0..56
    const int rV = tid >> 4;           // 0..15
    const int cV = (tid & 15) * 8;     // 0..120
    const bf16* kp = kg + (long)rK * 1536 + cK;
    const bf16* vp = vg + (long)rV * 2048 + cV;

    // swizzled LDS write offsets (elements); row&7 / row&15 invariant across +32m/+16m
    int kwo[4], vwo[4];
#pragma unroll
    for (int m = 0; m < 4; m++) {
        kwo[m] = (rK + 32 * m) * 64  + (((tid & 7)  ^ (rK & 7)) * 8);
        vwo[m] = (rV + 16 * m) * 128 + (((tid & 15) ^ rV) * 8);
    }
    // swizzled read bases (lane-constant parts)
    const int krow0   = l16 * 64;
    const int kchunkA = ((quad)     ^ (l16 & 7)) * 8;   // kf=0 chunk
    const int kchunkB = ((4 + quad) ^ (l16 & 7)) * 8;   // kf=1 chunk
    const int vrow0   = l16 * 128 + (quad & 1) * 4;     // within-chunk half from kv bit2
    const int vch0    = l16 ^ (quad >> 1);              // XOR with (hf*8 + kvt*2) per access

#pragma unroll 1
    for (int seg = 0; seg < 2; ++seg) {
        const int qb     = seg ? pb : (31 - pb);
        const int qblock = qb * 64;
        const int q0     = qblock + wid * 16;

        // Q fragment (B-operand for S^T): n=q=l16, k=d=kf*32+quad*8+e; pre-scaled by ls
        const bf16* qbase = qkv + (long)(b * 2048 + q0 + l16) * 1536 + h * 64;
        bf16x8 qf[2];
#pragma unroll
        for (int kf = 0; kf < 2; kf++) {
            const bf16* qp = qbase + kf * 32 + quad * 8;
            bf16 t8[8];
#pragma unroll
            for (int e = 0; e < 8; e++) t8[e] = __float2bfloat16(__bfloat162float(qp[e]) * ls);
            qf[kf] = *(const bf16x8*)t8;
        }

        f32x4 o[4] = {};          // O^T: q=l16, d = dt*16 + quad*4 + r
        f32x4 ol = {};            // l accumulator: every element = sum_kv P[kv][q=l16]

        // prologue: prefetch tile 0 of this segment (128 kv)
        uint4 kr[4], vr[4];
#pragma unroll
        for (int m = 0; m < 4; m++) {
            kr[m] = *(const uint4*)(kp + (long)(32 * m) * 1536);
            vr[m] = *(const uint4*)(vp + 16 * m * 2048);
        }

        const int nIter = qb / 2 + 1;
        for (int it = 0; it < nIter; ++it) {
            __syncthreads();   // WAR: prior iter (or prior segment) LDS reads done
#pragma unroll
            for (int m = 0; m < 4; m++) {
                *(uint4*)&Ksh[kwo[m]] = kr[m];
                *(uint4*)&Vsh[vwo[m]] = vr[m];
            }
            __syncthreads();

            // ---- prefetch tile it+1 (hides under compute below) ----
            if (it + 1 < nIter) {
                const long ko = (long)(it + 1) * 128 * 1536;
                const int  vo = (it + 1) * 128;
#pragma unroll
                for (int m = 0; m < 4; m++) {
                    kr[m] = *(const uint4*)(kp + ko + (long)(32 * m) * 1536);
                    vr[m] = *(const uint4*)(vp + vo + 16 * m * 2048);
                }
            }

            const bool lastT = (it == nIter - 1);
            // even qb: last tile's upper 64 kv fully masked -> skip that half
            const int nhalf = (lastT && !(qb & 1)) ? 1 : 2;
            for (int hf = 0; hf < nhalf; ++hf) {
                const bool diag = lastT && (hf == nhalf - 1);   // kv rel base == 0 here

                // ---- S^T = K Q^T : s[kvt]: q=l16, kv = hf*64 + kvt*16 + quad*4 + r ----
                f32x4 s[4] = {};
                __builtin_amdgcn_s_setprio(1);
#pragma unroll
                for (int kvt = 0; kvt < 4; kvt++) {
                    const int rbase = (hf * 64 + kvt * 16) * 64 + krow0;
                    const bf16x8 k0 = *(const bf16x8*)&Ksh[rbase + kchunkA];
                    s[kvt] = __builtin_amdgcn_mfma_f32_16x16x32_bf16(k0, qf[0], s[kvt], 0, 0, 0);
                    const bf16x8 k1 = *(const bf16x8*)&Ksh[rbase + kchunkB];
                    s[kvt] = __builtin_amdgcn_mfma_f32_16x16x32_bf16(k1, qf[1], s[kvt], 0, 0, 0);
                }
                __builtin_amdgcn_s_setprio(0);

                // ---- causal mask: only the diagonal half-tile ----
                if (diag) {
                    const int qq = wid * 16 + l16;
#pragma unroll
                    for (int kvt = 0; kvt < 4; kvt++)
#pragma unroll
                        for (int r = 0; r < 4; r++)
                            if (kvt * 16 + quad * 4 + r > qq) s[kvt][r] = -1e30f;
                }

                // ---- p = exp2(s); packed cvt; PV + l on matrix pipe ----
#pragma unroll
                for (int kvt = 0; kvt < 4; kvt++) {
                    float2 p01, p23;
                    p01.x = exp2f(s[kvt][0]);
                    p01.y = exp2f(s[kvt][1]);
                    p23.x = exp2f(s[kvt][2]);
                    p23.y = exp2f(s[kvt][3]);
                    __hip_bfloat162 pk01 = __float22bfloat162_rn(p01);
                    __hip_bfloat162 pk23 = __float22bfloat162_rn(p23);
                    bf16x4 pk;
                    *(__hip_bfloat162*)&pk       = pk01;
                    *((__hip_bfloat162*)&pk + 1) = pk23;

                    __builtin_amdgcn_s_setprio(1);
                    ol = __builtin_amdgcn_mfma_f32_16x16x16bf16_1k(ones, pk, ol, 0, 0, 0);
#pragma unroll
                    for (int dt = 0; dt < 4; dt++) {
                        const int vaddr = (dt * 16) * 128 + vrow0 +
                                          ((vch0 ^ (hf * 8 + kvt * 2)) * 8);
                        const bf16x4 vf = *(const bf16x4*)&Vsh[vaddr];
                        o[dt] = __builtin_amdgcn_mfma_f32_16x16x16bf16_1k(vf, pk, o[dt], 0, 0, 0);
                    }
                    __builtin_amdgcn_s_setprio(0);
                }
            }
        }

        // ---- epilogue: l complete per-lane; normalize + store O^T ----
        const float inv = 1.f / ol[0];
        bf16* obase = attn + (long)(b * 2048 + q0 + l16) * 1024 + h * 64;
#pragma unroll
        for (int dt = 0; dt < 4; dt++) {
            bf16 t4[4];
#pragma unroll
            for (int r = 0; r < 4; r++) t4[r] = __float2bfloat16(o[dt][r] * inv);
            *(uint2*)(obase + dt * 16 + quad * 4) = *(uint2*)t4;
        }
    }
}

// ---------------- launch ----------------
extern "C" void kernel_launch(void* const* d_in, const int* in_sizes, int n_in,
                              void* d_out, int out_size, void* d_ws, size_t ws_size,
                              hipStream_t stream) {
    const float* x  = (const float*)d_in[0];
    const float* wq = (const float*)d_in[1];
    const float* wk = (const float*)d_in[2];
    const float* wv = (const float*)d_in[3];
    const float* wo = (const float*)d_in[4];
    float* out = (float*)d_out;

    char* ws = (char*)d_ws;
    bf16* xb     = (bf16*)(ws);                       // 8192*1024
    bf16* wqkvT  = (bf16*)(ws + 16777216);            // 1536*1024
    bf16* woT    = (bf16*)(ws + 19922944);            // 1024*1024
    bf16* qkv    = (bf16*)(ws + 22020096);            // 8192*1536
    bf16* vt     = (bf16*)(ws + 47185920);            // 4*4*64*2048
    bf16* attn   = (bf16*)(ws + 51380224);            // 8192*1024

    cast_f32_bf16<<<8192, 256, 0, stream>>>(x, xb, 2097152);

    transpose_cast<<<dim3(32, 32), 256, 0, stream>>>(wq, 1024, 1024, wqkvT);
    transpose_cast<<<dim3(8, 32),  256, 0, stream>>>(wk, 1024, 256,  wqkvT + 1024 * 1024);
    transpose_cast<<<dim3(8, 32),  256, 0, stream>>>(wv, 1024, 256,  wqkvT + 1280 * 1024);
    transpose_cast<<<dim3(32, 32), 256, 0, stream>>>(wo, 1024, 1024, woT);

    gemm_bt<true><<<dim3(64, 12), 256, 0, stream>>>(xb, wqkvT, qkv, 8192, 1536, 1024);

    transpose_v<<<dim3(32, 4, 4), 256, 0, stream>>>(qkv, vt);

    attn_kernel<<<dim3(16, 16, 4), 256, 0, stream>>>(qkv, vt, attn);

    gemm_bt<false><<<dim3(64, 8), 256, 0, stream>>>(attn, woT, out, 8192, 1024, 1024);
}

// Round 2
// 241.515 us; speedup vs baseline: 1.4884x; 1.4884x over previous
//
#include <hip/hip_runtime.h>
#include <hip/hip_bf16.h>

using bf16 = __hip_bfloat16;
typedef __attribute__((ext_vector_type(8))) short bf16x8;   // 8 bf16 in 4 VGPRs
typedef __attribute__((ext_vector_type(4))) short bf16x4;   // 4 bf16 in 2 VGPRs
typedef __attribute__((ext_vector_type(4))) float f32x4;

// async global->LDS, 16B per lane; LDS dest = wave-uniform base + lane*16
typedef const __attribute__((address_space(1))) void* as1_t;
typedef __attribute__((address_space(3))) void* as3_t;
__device__ __forceinline__ void load_lds16(const void* g, void* l) {
    __builtin_amdgcn_global_load_lds((as1_t)g, (as3_t)l, 16, 0, 0);
}

// ---------------- elementwise cast f32 -> bf16 (x) ----------------
__global__ __launch_bounds__(256) void cast_f32_bf16(const float* __restrict__ src,
                                                     bf16* __restrict__ dst, int n4) {
    int i = (blockIdx.x * 256 + threadIdx.x);
    if (i >= n4) return;
    const float4 v = *(const float4*)(src + (long)i * 4);
    bf16 t[4];
    t[0] = __float2bfloat16(v.x);
    t[1] = __float2bfloat16(v.y);
    t[2] = __float2bfloat16(v.z);
    t[3] = __float2bfloat16(v.w);
    *(uint2*)(dst + (long)i * 4) = *(uint2*)t;
}

// ---------------- tiled transpose-cast: src[K][N] f32 -> dst[N][K] bf16 ----------------
__global__ __launch_bounds__(256) void transpose_cast(const float* __restrict__ src,
                                                      int K, int N, bf16* __restrict__ dst) {
    __shared__ float tile[32][33];
    const int tx = threadIdx.x & 31;
    const int ty = threadIdx.x >> 5;   // 0..7
    const int n0 = blockIdx.x * 32;
    const int k0 = blockIdx.y * 32;
    for (int i = 0; i < 32; i += 8)
        tile[ty + i][tx] = src[(long)(k0 + ty + i) * N + n0 + tx];
    __syncthreads();
    for (int i = 0; i < 32; i += 8)
        dst[(long)(n0 + ty + i) * K + k0 + tx] = __float2bfloat16(tile[tx][ty + i]);
}

// ---------------- V transpose via LDS tile: qkv[8192][1536] -> vt[b][kvh][64][2048] ----------------
__global__ __launch_bounds__(256) void transpose_v(const bf16* __restrict__ qkv,
                                                   bf16* __restrict__ vt) {
    __shared__ bf16 tile[64][72];
    const int tb = blockIdx.x, kvh = blockIdx.y, b = blockIdx.z;
    const int r = threadIdx.x >> 3;          // 0..31
    const int c = (threadIdx.x & 7) * 8;     // 0..56
    const bf16* src = qkv + (long)(b * 2048 + tb * 64) * 1536 + 1280 + kvh * 64;
    *(uint4*)&tile[r][c]      = *(const uint4*)(src + (long)r * 1536 + c);
    *(uint4*)&tile[r + 32][c] = *(const uint4*)(src + (long)(r + 32) * 1536 + c);
    __syncthreads();
    bf16* dst = vt + (long)(b * 4 + kvh) * 64 * 2048 + tb * 64;
#pragma unroll
    for (int rr = 0; rr < 2; rr++) {
        const int d = r + rr * 32;
        bf16 t8[8];
#pragma unroll
        for (int e = 0; e < 8; e++) t8[e] = tile[c + e][d];
        *(uint4*)(dst + (long)d * 2048 + c) = *(uint4*)t8;
    }
}

// ---------------- GEMM (m97 structure): C[M][N] = A[M][K] * Bt[N][K]^T ----------------
template <bool BF16_OUT>
__global__ __launch_bounds__(256) void gemm_bt(const bf16* __restrict__ A,
                                               const bf16* __restrict__ Bt,
                                               void* __restrict__ C,
                                               int M, int N, int K) {
    __shared__ bf16 Ash[128 * 32];
    __shared__ bf16 Bsh[128 * 32];
    const int tid  = threadIdx.x;
    const int lane = tid & 63;
    const int wid  = tid >> 6;
    const int wm   = (wid >> 1) * 64;
    const int wn   = (wid & 1) * 64;
    const int quad = lane >> 4;
    const int l16  = lane & 15;
    const int bm = blockIdx.x, bn = blockIdx.y;

    const int r_l   = lane >> 2;                 // 0..15
    const int cslot = lane & 3;
    const int cdat  = (cslot - (r_l >> 1)) & 3;  // swizzled source chunk

    const bf16* pa0 = A  + (long)(bm * 128 + wid * 32 + r_l) * K + cdat * 8;
    const bf16* pa1 = pa0 + (long)16 * K;
    const bf16* pb0 = Bt + (long)(bn * 128 + wid * 32 + r_l) * K + cdat * 8;
    const bf16* pb1 = pb0 + (long)16 * K;
    bf16* la0 = Ash + (wid * 32) * 32;
    bf16* la1 = Ash + (wid * 32 + 16) * 32;
    bf16* lb0 = Bsh + (wid * 32) * 32;
    bf16* lb1 = Bsh + (wid * 32 + 16) * 32;

    const int sw = ((quad + (l16 >> 1)) & 3) * 8;   // swizzled chunk for frag reads

    f32x4 acc[4][4] = {};

    for (int k0 = 0; k0 < K; k0 += 32) {
        __syncthreads();
        load_lds16(pa0 + k0, la0);
        load_lds16(pa1 + k0, la1);
        load_lds16(pb0 + k0, lb0);
        load_lds16(pb1 + k0, lb1);
        __syncthreads();

        bf16x8 af[4], bfr[4];
#pragma unroll
        for (int i = 0; i < 4; i++) af[i]  = *(const bf16x8*)&Ash[(wm + i * 16 + l16) * 32 + sw];
#pragma unroll
        for (int j = 0; j < 4; j++) bfr[j] = *(const bf16x8*)&Bsh[(wn + j * 16 + l16) * 32 + sw];
#pragma unroll
        for (int i = 0; i < 4; i++)
#pragma unroll
            for (int j = 0; j < 4; j++)
                acc[i][j] = __builtin_amdgcn_mfma_f32_16x16x32_bf16(af[i], bfr[j], acc[i][j], 0, 0, 0);
    }

#pragma unroll
    for (int i = 0; i < 4; i++) {
#pragma unroll
        for (int r = 0; r < 4; r++) {
            const long row = (long)(bm * 128 + wm + i * 16 + quad * 4 + r);
#pragma unroll
            for (int j = 0; j < 4; j++) {
                const int col = bn * 128 + wn + j * 16 + l16;
                const float v = acc[i][j][r];
                if (BF16_OUT) ((bf16*)C)[row * N + col] = __float2bfloat16(v);
                else          ((float*)C)[row * N + col] = v;
            }
        }
    }
}

// ---------------- flash attention v9: v7 structure + XOR-swizzled LDS (T2 only) ----------------
// grid: (T/128, NH, B) = (16,16,4); 256 threads = 4 waves; wave owns 16 q rows.
// Each block processes TWO q-blocks {31-pb, pb}: (32-pb) + (pb+1) = 33 tile-iters
// for every block -> zero causal imbalance, occupancy sustained to the end.
// v8's KVBLK=128 + runtime inner loop caused register->scratch demotion (573MB
// scratch writes, rule #20); reverted to v7's straight-line body. ONLY change vs
// v7: LDS tiles are flat [64*64] with 16B-chunk XOR swizzle (chunk ^= row&7).
//   K b128 read:  slot = (kf*4+quad) ^ (l16&7) -> each 8-lane group covers all
//                 8 slots (v7's 72-pad left l16+quad aliasing).
//   V b64  read:  slot = (kvt*2+(quad>>1)) ^ (l16&7), +8B half from quad&1 ->
//                 distinct per 8-lane group (v7 was ~4-way: 4*l16+2*quad mod 32
//                 collides at (l16+1,q-2) and l16+8; no pad can fix it at 16B align).
// All swizzle terms are lane-constant; zero extra VALU in the hot loop.
__global__ __launch_bounds__(256) void attn_kernel(const bf16* __restrict__ qkv,
                                                   const bf16* __restrict__ vt,
                                                   bf16* __restrict__ attn) {
    __shared__ bf16 Ksh[64 * 64];     // [kv][d], chunk ^= kv&7
    __shared__ bf16 Vsh[64 * 64];     // [d][kv], chunk ^= d&7

    const int tid  = threadIdx.x;
    const int lane = tid & 63;
    const int wid  = tid >> 6;
    const int quad = lane >> 4;
    const int l16  = lane & 15;
    const int h    = blockIdx.y;
    const int b    = blockIdx.z;
    const int kvh  = h >> 2;
    const int pb   = blockIdx.x;      // 0..15

    const float ls = 0.125f * 1.44269504f;   // 1/sqrt(64) * log2(e)

    // ones fragment for l-accumulation MFMA (A[m][k] = 1.0)
    bf16x4 ones;
    { short o1 = (short)0x3F80; short t4[4] = {o1, o1, o1, o1}; ones = *(const bf16x4*)t4; }

    const bf16* kg = qkv + (long)(b * 2048) * 1536 + 1024 + kvh * 64;
    const bf16* vg = vt + (long)(b * 4 + kvh) * 64 * 2048;
    const int r0 = tid >> 3;          // 0..31
    const int ch0 = tid & 7;          // source 16B chunk 0..7
    const int c0 = ch0 * 8;

    const bf16* kp0 = kg + (long)r0 * 1536 + c0;
    const bf16* kp1 = kp0 + (long)32 * 1536;
    const bf16* vp0 = vg + (long)r0 * 2048 + c0;
    const bf16* vp1 = vp0 + (long)32 * 2048;

    // swizzled LDS write offsets (elements); (r0+32)&7 == r0&7
    const int wo0 = r0 * 64 + ((ch0 ^ (r0 & 7)) * 8);
    const int wo1 = wo0 + 32 * 64;
    // swizzled read address lane-constants
    const int kchunkA = (quad ^ (l16 & 7)) * 8;         // kf=0: chunk = quad
    const int kchunkB = ((4 + quad) ^ (l16 & 7)) * 8;   // kf=1: chunk = 4+quad
    const int vsub    = (quad & 1) * 4;                 // low/high half of 8-elem chunk
    const int vq      = quad >> 1;

#pragma unroll 1
    for (int seg = 0; seg < 2; ++seg) {
        const int qb     = seg ? pb : (31 - pb);
        const int qblock = qb * 64;
        const int q0     = qblock + wid * 16;

        // Q fragment (B-operand for S^T): n=q=l16, k=d=kf*32+quad*8+e; pre-scaled by ls
        const bf16* qbase = qkv + (long)(b * 2048 + q0 + l16) * 1536 + h * 64;
        bf16x8 qf[2];
#pragma unroll
        for (int kf = 0; kf < 2; kf++) {
            const bf16* qp = qbase + kf * 32 + quad * 8;
            bf16 t8[8];
#pragma unroll
            for (int e = 0; e < 8; e++) t8[e] = __float2bfloat16(__bfloat162float(qp[e]) * ls);
            qf[kf] = *(const bf16x8*)t8;
        }

        f32x4 o[4] = {};          // O^T: q=l16, d = dt*16 + quad*4 + r
        f32x4 ol = {};            // l accumulator: every element = sum_kv P[kv][q=l16]

        // prologue: prefetch tile 0 of this segment
        uint4 kr0 = *(const uint4*)kp0;
        uint4 kr1 = *(const uint4*)kp1;
        uint4 vr0 = *(const uint4*)vp0;
        uint4 vr1 = *(const uint4*)vp1;

        const int nIter = qb + 1;
        for (int it = 0; it < nIter; ++it) {
            __syncthreads();   // WAR: prior iter (or prior segment) LDS reads done
            *(uint4*)&Ksh[wo0] = kr0;
            *(uint4*)&Ksh[wo1] = kr1;
            *(uint4*)&Vsh[wo0] = vr0;
            *(uint4*)&Vsh[wo1] = vr1;
            __syncthreads();

            // ---- prefetch tile it+1 (hides under compute below) ----
            if (it + 1 < nIter) {
                const long ko = (long)(it + 1) * 64 * 1536;
                const long vo = (it + 1) * 64;
                kr0 = *(const uint4*)(kp0 + ko);
                kr1 = *(const uint4*)(kp1 + ko);
                vr0 = *(const uint4*)(vp0 + vo);
                vr1 = *(const uint4*)(vp1 + vo);
            }

            // ---- S^T = K Q^T : s[kvt]: q=l16, kv = it*64 + kvt*16 + quad*4 + r ----
            f32x4 s[4] = {};
#pragma unroll
            for (int kvt = 0; kvt < 4; kvt++)
#pragma unroll
                for (int kf = 0; kf < 2; kf++) {
                    const int rbase = (kvt * 16 + l16) * 64;
                    const bf16x8 kfr = *(const bf16x8*)&Ksh[rbase + (kf ? kchunkB : kchunkA)];
                    s[kvt] = __builtin_amdgcn_mfma_f32_16x16x32_bf16(kfr, qf[kf], s[kvt], 0, 0, 0);
                }

            // ---- causal mask: only the diagonal tile ----
            if (it == nIter - 1) {
                const int qq = wid * 16 + l16;
#pragma unroll
                for (int kvt = 0; kvt < 4; kvt++)
#pragma unroll
                    for (int r = 0; r < 4; r++)
                        if (kvt * 16 + quad * 4 + r > qq) s[kvt][r] = -1e30f;
            }

            // ---- p = exp2(s); packed cvt; PV + l on matrix pipe ----
#pragma unroll
            for (int kvt = 0; kvt < 4; kvt++) {
                float2 p01, p23;
                p01.x = exp2f(s[kvt][0]);
                p01.y = exp2f(s[kvt][1]);
                p23.x = exp2f(s[kvt][2]);
                p23.y = exp2f(s[kvt][3]);
                __hip_bfloat162 pk01 = __float22bfloat162_rn(p01);
                __hip_bfloat162 pk23 = __float22bfloat162_rn(p23);
                bf16x4 pk;
                *(__hip_bfloat162*)&pk       = pk01;
                *((__hip_bfloat162*)&pk + 1) = pk23;

                ol = __builtin_amdgcn_mfma_f32_16x16x16bf16_1k(ones, pk, ol, 0, 0, 0);
#pragma unroll
                for (int dt = 0; dt < 4; dt++) {
                    // V element (d = dt*16+l16, kv = kvt*16+quad*4+r):
                    // chunk = (kvt*2 + (quad>>1)) ^ (l16&7), sub = (quad&1)*4
                    const int vaddr = (dt * 16 + l16) * 64 +
                                      (((kvt * 2 + vq) ^ (l16 & 7)) * 8) + vsub;
                    const bf16x4 vf = *(const bf16x4*)&Vsh[vaddr];
                    o[dt] = __builtin_amdgcn_mfma_f32_16x16x16bf16_1k(vf, pk, o[dt], 0, 0, 0);
                }
            }
        }

        // ---- epilogue: l complete per-lane; normalize + store O^T ----
        const float inv = 1.f / ol[0];
        bf16* obase = attn + (long)(b * 2048 + q0 + l16) * 1024 + h * 64;
#pragma unroll
        for (int dt = 0; dt < 4; dt++) {
            bf16 t4[4];
#pragma unroll
            for (int r = 0; r < 4; r++) t4[r] = __float2bfloat16(o[dt][r] * inv);
            *(uint2*)(obase + dt * 16 + quad * 4) = *(uint2*)t4;
        }
    }
}

// ---------------- launch ----------------
extern "C" void kernel_launch(void* const* d_in, const int* in_sizes, int n_in,
                              void* d_out, int out_size, void* d_ws, size_t ws_size,
                              hipStream_t stream) {
    const float* x  = (const float*)d_in[0];
    const float* wq = (const float*)d_in[1];
    const float* wk = (const float*)d_in[2];
    const float* wv = (const float*)d_in[3];
    const float* wo = (const float*)d_in[4];
    float* out = (float*)d_out;

    char* ws = (char*)d_ws;
    bf16* xb     = (bf16*)(ws);                       // 8192*1024
    bf16* wqkvT  = (bf16*)(ws + 16777216);            // 1536*1024
    bf16* woT    = (bf16*)(ws + 19922944);            // 1024*1024
    bf16* qkv    = (bf16*)(ws + 22020096);            // 8192*1536
    bf16* vt     = (bf16*)(ws + 47185920);            // 4*4*64*2048
    bf16* attn   = (bf16*)(ws + 51380224);            // 8192*1024

    cast_f32_bf16<<<8192, 256, 0, stream>>>(x, xb, 2097152);

    transpose_cast<<<dim3(32, 32), 256, 0, stream>>>(wq, 1024, 1024, wqkvT);
    transpose_cast<<<dim3(8, 32),  256, 0, stream>>>(wk, 1024, 256,  wqkvT + 1024 * 1024);
    transpose_cast<<<dim3(8, 32),  256, 0, stream>>>(wv, 1024, 256,  wqkvT + 1280 * 1024);
    transpose_cast<<<dim3(32, 32), 256, 0, stream>>>(wo, 1024, 1024, woT);

    gemm_bt<true><<<dim3(64, 12), 256, 0, stream>>>(xb, wqkvT, qkv, 8192, 1536, 1024);

    transpose_v<<<dim3(32, 4, 4), 256, 0, stream>>>(qkv, vt);

    attn_kernel<<<dim3(16, 16, 4), 256, 0, stream>>>(qkv, vt, attn);

    gemm_bt<false><<<dim3(64, 8), 256, 0, stream>>>(attn, woT, out, 8192, 1024, 1024);
}

// Round 4
// 229.357 us; speedup vs baseline: 1.5673x; 1.0530x over previous
//
#include <hip/hip_runtime.h>
#include <hip/hip_bf16.h>

using bf16 = __hip_bfloat16;
typedef __attribute__((ext_vector_type(8))) short bf16x8;   // 8 bf16 in 4 VGPRs
typedef __attribute__((ext_vector_type(4))) short bf16x4;   // 4 bf16 in 2 VGPRs
typedef __attribute__((ext_vector_type(4))) float f32x4;

// async global->LDS, 16B per lane; LDS dest = wave-uniform base + lane*16
typedef const __attribute__((address_space(1))) void* as1_t;
typedef __attribute__((address_space(3))) void* as3_t;
__device__ __forceinline__ void load_lds16(const void* g, void* l) {
    __builtin_amdgcn_global_load_lds((as1_t)g, (as3_t)l, 16, 0, 0);
}

// exp2 as a single v_exp_f32 via COMPILER-VISIBLE builtin (not inline asm: the v10
// inline-asm variant NaN'd - INLINEASM producers are invisible to the hazard
// recognizer feeding MFMA). OCML exp2f libcall is ~7-10 VALU; this is 1 TRANS op.
#if !__has_builtin(__builtin_amdgcn_exp2f)
extern "C" __device__ float __ocml_native_exp2_f32(float);
#endif
__device__ __forceinline__ float exp2_fast(float x) {
#if __has_builtin(__builtin_amdgcn_exp2f)
    return __builtin_amdgcn_exp2f(x);
#else
    return __ocml_native_exp2_f32(x);
#endif
}

// ---------------- elementwise cast f32 -> bf16 (x) ----------------
__global__ __launch_bounds__(256) void cast_f32_bf16(const float* __restrict__ src,
                                                     bf16* __restrict__ dst, int n4) {
    int i = (blockIdx.x * 256 + threadIdx.x);
    if (i >= n4) return;
    const float4 v = *(const float4*)(src + (long)i * 4);
    bf16 t[4];
    t[0] = __float2bfloat16(v.x);
    t[1] = __float2bfloat16(v.y);
    t[2] = __float2bfloat16(v.z);
    t[3] = __float2bfloat16(v.w);
    *(uint2*)(dst + (long)i * 4) = *(uint2*)t;
}

// ---------------- tiled transpose-cast: src[K][N] f32 -> dst[N][K] bf16 ----------------
__global__ __launch_bounds__(256) void transpose_cast(const float* __restrict__ src,
                                                      int K, int N, bf16* __restrict__ dst) {
    __shared__ float tile[32][33];
    const int tx = threadIdx.x & 31;
    const int ty = threadIdx.x >> 5;   // 0..7
    const int n0 = blockIdx.x * 32;
    const int k0 = blockIdx.y * 32;
    for (int i = 0; i < 32; i += 8)
        tile[ty + i][tx] = src[(long)(k0 + ty + i) * N + n0 + tx];
    __syncthreads();
    for (int i = 0; i < 32; i += 8)
        dst[(long)(n0 + ty + i) * K + k0 + tx] = __float2bfloat16(tile[tx][ty + i]);
}

// ---------------- V transpose via LDS tile: qkv[8192][1536] -> vt[b][kvh][64][2048] ----------------
__global__ __launch_bounds__(256) void transpose_v(const bf16* __restrict__ qkv,
                                                   bf16* __restrict__ vt) {
    __shared__ bf16 tile[64][72];
    const int tb = blockIdx.x, kvh = blockIdx.y, b = blockIdx.z;
    const int r = threadIdx.x >> 3;          // 0..31
    const int c = (threadIdx.x & 7) * 8;     // 0..56
    const bf16* src = qkv + (long)(b * 2048 + tb * 64) * 1536 + 1280 + kvh * 64;
    *(uint4*)&tile[r][c]      = *(const uint4*)(src + (long)r * 1536 + c);
    *(uint4*)&tile[r + 32][c] = *(const uint4*)(src + (long)(r + 32) * 1536 + c);
    __syncthreads();
    bf16* dst = vt + (long)(b * 4 + kvh) * 64 * 2048 + tb * 64;
#pragma unroll
    for (int rr = 0; rr < 2; rr++) {
        const int d = r + rr * 32;
        bf16 t8[8];
#pragma unroll
        for (int e = 0; e < 8; e++) t8[e] = tile[c + e][d];
        *(uint4*)(dst + (long)d * 2048 + c) = *(uint4*)t8;
    }
}

// ---------------- GEMM (m97 structure): C[M][N] = A[M][K] * Bt[N][K]^T ----------------
template <bool BF16_OUT>
__global__ __launch_bounds__(256) void gemm_bt(const bf16* __restrict__ A,
                                               const bf16* __restrict__ Bt,
                                               void* __restrict__ C,
                                               int M, int N, int K) {
    __shared__ bf16 Ash[128 * 32];
    __shared__ bf16 Bsh[128 * 32];
    const int tid  = threadIdx.x;
    const int lane = tid & 63;
    const int wid  = tid >> 6;
    const int wm   = (wid >> 1) * 64;
    const int wn   = (wid & 1) * 64;
    const int quad = lane >> 4;
    const int l16  = lane & 15;
    const int bm = blockIdx.x, bn = blockIdx.y;

    const int r_l   = lane >> 2;                 // 0..15
    const int cslot = lane & 3;
    const int cdat  = (cslot - (r_l >> 1)) & 3;  // swizzled source chunk

    const bf16* pa0 = A  + (long)(bm * 128 + wid * 32 + r_l) * K + cdat * 8;
    const bf16* pa1 = pa0 + (long)16 * K;
    const bf16* pb0 = Bt + (long)(bn * 128 + wid * 32 + r_l) * K + cdat * 8;
    const bf16* pb1 = pb0 + (long)16 * K;
    bf16* la0 = Ash + (wid * 32) * 32;
    bf16* la1 = Ash + (wid * 32 + 16) * 32;
    bf16* lb0 = Bsh + (wid * 32) * 32;
    bf16* lb1 = Bsh + (wid * 32 + 16) * 32;

    const int sw = ((quad + (l16 >> 1)) & 3) * 8;   // swizzled chunk for frag reads

    f32x4 acc[4][4] = {};

    for (int k0 = 0; k0 < K; k0 += 32) {
        __syncthreads();
        load_lds16(pa0 + k0, la0);
        load_lds16(pa1 + k0, la1);
        load_lds16(pb0 + k0, lb0);
        load_lds16(pb1 + k0, lb1);
        __syncthreads();

        bf16x8 af[4], bfr[4];
#pragma unroll
        for (int i = 0; i < 4; i++) af[i]  = *(const bf16x8*)&Ash[(wm + i * 16 + l16) * 32 + sw];
#pragma unroll
        for (int j = 0; j < 4; j++) bfr[j] = *(const bf16x8*)&Bsh[(wn + j * 16 + l16) * 32 + sw];
#pragma unroll
        for (int i = 0; i < 4; i++)
#pragma unroll
            for (int j = 0; j < 4; j++)
                acc[i][j] = __builtin_amdgcn_mfma_f32_16x16x32_bf16(af[i], bfr[j], acc[i][j], 0, 0, 0);
    }

#pragma unroll
    for (int i = 0; i < 4; i++) {
#pragma unroll
        for (int r = 0; r < 4; r++) {
            const long row = (long)(bm * 128 + wm + i * 16 + quad * 4 + r);
#pragma unroll
            for (int j = 0; j < 4; j++) {
                const int col = bn * 128 + wn + j * 16 + l16;
                const float v = acc[i][j][r];
                if (BF16_OUT) ((bf16*)C)[row * N + col] = __float2bfloat16(v);
                else          ((float*)C)[row * N + col] = v;
            }
        }
    }
}

// ---------------- flash attention v11: v9 structure + builtin exp2 (single change) ----------------
// grid: (T/128, NH, B) = (16,16,4); 256 threads = 4 waves; wave owns 16 q rows.
// Each block processes TWO q-blocks {31-pb, pb}: (32-pb) + (pb+1) = 33 tile-iters.
// v10 post-mortem: inline-asm exp2/cvt_pk feeding MFMA NaN'd (INLINEASM is invisible
// to the hazard recognizer); dbuf unproven. v11 = v9 EXACTLY (passing, 86.5us) with
// ONE change: exp2f -> __builtin_amdgcn_exp2f (1 TRANS op, compiler-visible, vs
// OCML's ~8-VALU libcall x16/iter on the S->P critical path; v9 counters back-solve
// to ~150-200 VALU/iter vs 28 MFMA = the observed 54% VALUBusy). Pack stays
// __float22bfloat162_rn (m240: scalar-cast path compiles well; asm pack is harmful).
__global__ __launch_bounds__(256) void attn_kernel(const bf16* __restrict__ qkv,
                                                   const bf16* __restrict__ vt,
                                                   bf16* __restrict__ attn) {
    __shared__ bf16 Ksh[64 * 64];     // [kv][d], chunk ^= kv&7
    __shared__ bf16 Vsh[64 * 64];     // [d][kv], chunk ^= d&7

    const int tid  = threadIdx.x;
    const int lane = tid & 63;
    const int wid  = tid >> 6;
    const int quad = lane >> 4;
    const int l16  = lane & 15;
    const int h    = blockIdx.y;
    const int b    = blockIdx.z;
    const int kvh  = h >> 2;
    const int pb   = blockIdx.x;      // 0..15

    const float ls = 0.125f * 1.44269504f;   // 1/sqrt(64) * log2(e)

    // ones fragment for l-accumulation MFMA (A[m][k] = 1.0)
    bf16x4 ones;
    { short o1 = (short)0x3F80; short t4[4] = {o1, o1, o1, o1}; ones = *(const bf16x4*)t4; }

    const bf16* kg = qkv + (long)(b * 2048) * 1536 + 1024 + kvh * 64;
    const bf16* vg = vt + (long)(b * 4 + kvh) * 64 * 2048;
    const int r0 = tid >> 3;          // 0..31
    const int ch0 = tid & 7;          // source 16B chunk 0..7
    const int c0 = ch0 * 8;

    const bf16* kp0 = kg + (long)r0 * 1536 + c0;
    const bf16* kp1 = kp0 + (long)32 * 1536;
    const bf16* vp0 = vg + (long)r0 * 2048 + c0;
    const bf16* vp1 = vp0 + (long)32 * 2048;

    // swizzled LDS write offsets (elements); (r0+32)&7 == r0&7
    const int wo0 = r0 * 64 + ((ch0 ^ (r0 & 7)) * 8);
    const int wo1 = wo0 + 32 * 64;
    // swizzled read address lane-constants
    const int kchunkA = (quad ^ (l16 & 7)) * 8;         // kf=0: chunk = quad
    const int kchunkB = ((4 + quad) ^ (l16 & 7)) * 8;   // kf=1: chunk = 4+quad
    const int vsub    = (quad & 1) * 4;                 // low/high half of 8-elem chunk
    const int vq      = quad >> 1;

#pragma unroll 1
    for (int seg = 0; seg < 2; ++seg) {
        const int qb     = seg ? pb : (31 - pb);
        const int qblock = qb * 64;
        const int q0     = qblock + wid * 16;

        // Q fragment (B-operand for S^T): n=q=l16, k=d=kf*32+quad*8+e; pre-scaled by ls
        const bf16* qbase = qkv + (long)(b * 2048 + q0 + l16) * 1536 + h * 64;
        bf16x8 qf[2];
#pragma unroll
        for (int kf = 0; kf < 2; kf++) {
            const bf16* qp = qbase + kf * 32 + quad * 8;
            bf16 t8[8];
#pragma unroll
            for (int e = 0; e < 8; e++) t8[e] = __float2bfloat16(__bfloat162float(qp[e]) * ls);
            qf[kf] = *(const bf16x8*)t8;
        }

        f32x4 o[4] = {};          // O^T: q=l16, d = dt*16 + quad*4 + r
        f32x4 ol = {};            // l accumulator: every element = sum_kv P[kv][q=l16]

        // prologue: prefetch tile 0 of this segment
        uint4 kr0 = *(const uint4*)kp0;
        uint4 kr1 = *(const uint4*)kp1;
        uint4 vr0 = *(const uint4*)vp0;
        uint4 vr1 = *(const uint4*)vp1;

        const int nIter = qb + 1;
        for (int it = 0; it < nIter; ++it) {
            __syncthreads();   // WAR: prior iter (or prior segment) LDS reads done
            *(uint4*)&Ksh[wo0] = kr0;
            *(uint4*)&Ksh[wo1] = kr1;
            *(uint4*)&Vsh[wo0] = vr0;
            *(uint4*)&Vsh[wo1] = vr1;
            __syncthreads();

            // ---- prefetch tile it+1 (hides under compute below) ----
            if (it + 1 < nIter) {
                const long ko = (long)(it + 1) * 64 * 1536;
                const long vo = (it + 1) * 64;
                kr0 = *(const uint4*)(kp0 + ko);
                kr1 = *(const uint4*)(kp1 + ko);
                vr0 = *(const uint4*)(vp0 + vo);
                vr1 = *(const uint4*)(vp1 + vo);
            }

            // ---- S^T = K Q^T : s[kvt]: q=l16, kv = it*64 + kvt*16 + quad*4 + r ----
            f32x4 s[4] = {};
#pragma unroll
            for (int kvt = 0; kvt < 4; kvt++)
#pragma unroll
                for (int kf = 0; kf < 2; kf++) {
                    const int rbase = (kvt * 16 + l16) * 64;
                    const bf16x8 kfr = *(const bf16x8*)&Ksh[rbase + (kf ? kchunkB : kchunkA)];
                    s[kvt] = __builtin_amdgcn_mfma_f32_16x16x32_bf16(kfr, qf[kf], s[kvt], 0, 0, 0);
                }

            // ---- causal mask: only the diagonal tile ----
            if (it == nIter - 1) {
                const int qq = wid * 16 + l16;
#pragma unroll
                for (int kvt = 0; kvt < 4; kvt++)
#pragma unroll
                    for (int r = 0; r < 4; r++)
                        if (kvt * 16 + quad * 4 + r > qq) s[kvt][r] = -1e30f;
            }

            // ---- p = exp2(s) [1 TRANS op each]; packed cvt; PV + l on matrix pipe ----
#pragma unroll
            for (int kvt = 0; kvt < 4; kvt++) {
                float2 p01, p23;
                p01.x = exp2_fast(s[kvt][0]);
                p01.y = exp2_fast(s[kvt][1]);
                p23.x = exp2_fast(s[kvt][2]);
                p23.y = exp2_fast(s[kvt][3]);
                __hip_bfloat162 pk01 = __float22bfloat162_rn(p01);
                __hip_bfloat162 pk23 = __float22bfloat162_rn(p23);
                bf16x4 pk;
                *(__hip_bfloat162*)&pk       = pk01;
                *((__hip_bfloat162*)&pk + 1) = pk23;

                ol = __builtin_amdgcn_mfma_f32_16x16x16bf16_1k(ones, pk, ol, 0, 0, 0);
#pragma unroll
                for (int dt = 0; dt < 4; dt++) {
                    // V element (d = dt*16+l16, kv = kvt*16+quad*4+r):
                    // chunk = (kvt*2 + (quad>>1)) ^ (l16&7), sub = (quad&1)*4
                    const int vaddr = (dt * 16 + l16) * 64 +
                                      (((kvt * 2 + vq) ^ (l16 & 7)) * 8) + vsub;
                    const bf16x4 vf = *(const bf16x4*)&Vsh[vaddr];
                    o[dt] = __builtin_amdgcn_mfma_f32_16x16x16bf16_1k(vf, pk, o[dt], 0, 0, 0);
                }
            }
        }

        // ---- epilogue: l complete per-lane; normalize + store O^T ----
        const float inv = 1.f / ol[0];
        bf16* obase = attn + (long)(b * 2048 + q0 + l16) * 1024 + h * 64;
#pragma unroll
        for (int dt = 0; dt < 4; dt++) {
            bf16 t4[4];
#pragma unroll
            for (int r = 0; r < 4; r++) t4[r] = __float2bfloat16(o[dt][r] * inv);
            *(uint2*)(obase + dt * 16 + quad * 4) = *(uint2*)t4;
        }
    }
}

// ---------------- launch ----------------
extern "C" void kernel_launch(void* const* d_in, const int* in_sizes, int n_in,
                              void* d_out, int out_size, void* d_ws, size_t ws_size,
                              hipStream_t stream) {
    const float* x  = (const float*)d_in[0];
    const float* wq = (const float*)d_in[1];
    const float* wk = (const float*)d_in[2];
    const float* wv = (const float*)d_in[3];
    const float* wo = (const float*)d_in[4];
    float* out = (float*)d_out;

    char* ws = (char*)d_ws;
    bf16* xb     = (bf16*)(ws);                       // 8192*1024
    bf16* wqkvT  = (bf16*)(ws + 16777216);            // 1536*1024
    bf16* woT    = (bf16*)(ws + 19922944);            // 1024*1024
    bf16* qkv    = (bf16*)(ws + 22020096);            // 8192*1536
    bf16* vt     = (bf16*)(ws + 47185920);            // 4*4*64*2048
    bf16* attn   = (bf16*)(ws + 51380224);            // 8192*1024

    cast_f32_bf16<<<8192, 256, 0, stream>>>(x, xb, 2097152);

    transpose_cast<<<dim3(32, 32), 256, 0, stream>>>(wq, 1024, 1024, wqkvT);
    transpose_cast<<<dim3(8, 32),  256, 0, stream>>>(wk, 1024, 256,  wqkvT + 1024 * 1024);
    transpose_cast<<<dim3(8, 32),  256, 0, stream>>>(wv, 1024, 256,  wqkvT + 1280 * 1024);
    transpose_cast<<<dim3(32, 32), 256, 0, stream>>>(wo, 1024, 1024, woT);

    gemm_bt<true><<<dim3(64, 12), 256, 0, stream>>>(xb, wqkvT, qkv, 8192, 1536, 1024);

    transpose_v<<<dim3(32, 4, 4), 256, 0, stream>>>(qkv, vt);

    attn_kernel<<<dim3(16, 16, 4), 256, 0, stream>>>(qkv, vt, attn);

    gemm_bt<false><<<dim3(64, 8), 256, 0, stream>>>(attn, woT, out, 8192, 1024, 1024);
}